// Round 1
// baseline (1960.476 us; speedup 1.0000x reference)
//
#include <hip/hip_runtime.h>
#include <math.h>

#define NN 20000
#define EE 640000
#define HH 128
#define LL 12
#define DOUT_ 16
#define EPS_ 1e-7f
#define LN_EPS_ 1e-5f

// ---------------- CSR build ----------------
__global__ __launch_bounds__(256) void hist_kernel(const int* __restrict__ dst, int* __restrict__ deg) {
  int e = blockIdx.x * 256 + threadIdx.x;
  if (e < EE) atomicAdd(&deg[dst[e]], 1);
}

__global__ __launch_bounds__(1024) void scan_kernel(const int* __restrict__ deg, int* __restrict__ off,
                                                    int* __restrict__ cur) {
  __shared__ int part[1024];
  int tid = threadIdx.x;
  const int CH = (NN + 1023) >> 10;   // 20
  int base = tid * CH;
  int s = 0;
  for (int j = 0; j < CH; ++j) { int i = base + j; if (i < NN) s += deg[i]; }
  part[tid] = s;
  __syncthreads();
  for (int d = 1; d < 1024; d <<= 1) {
    int v = (tid >= d) ? part[tid - d] : 0;
    __syncthreads();
    part[tid] += v;
    __syncthreads();
  }
  int run = part[tid] - s;  // exclusive prefix
  for (int j = 0; j < CH; ++j) {
    int i = base + j;
    if (i < NN) { off[i] = run; cur[i] = run; run += deg[i]; }
  }
  if (tid == 1023) off[NN] = part[1023];
}

__global__ __launch_bounds__(256) void scatter_kernel(const int* __restrict__ src, const int* __restrict__ dst,
                                                      const float4* __restrict__ ea, int* __restrict__ cur,
                                                      int* __restrict__ srcs, float4* __restrict__ ea4) {
  int e = blockIdx.x * 256 + threadIdx.x;
  if (e >= EE) return;
  int d = dst[e];
  int p = atomicAdd(&cur[d], 1);
  srcs[p] = src[e];
  ea4[p] = ea[e];
}

// ---------------- encoders ----------------
__global__ __launch_bounds__(256) void encoder_kernel(const float* __restrict__ x, const float* __restrict__ w,
                                                      const float* __restrict__ b, float* __restrict__ h) {
  int id = blockIdx.x * 256 + threadIdx.x;
  if (id >= NN * HH) return;
  int n = id >> 7, c = id & 127;
  h[id] = b[c] + x[n*3+0]*w[c] + x[n*3+1]*w[HH+c] + x[n*3+2]*w[2*HH+c];
}

// ---------------- LN + ReLU over H=128 (wave per node) ----------------
__global__ __launch_bounds__(256) void lnrelu_kernel(const float* __restrict__ h, const float* __restrict__ g,
                                                     const float* __restrict__ b, float* __restrict__ out) {
  int wid = blockIdx.x * 4 + (threadIdx.x >> 6);
  int lane = threadIdx.x & 63;
  if (wid >= NN) return;
  int c0 = lane * 2;
  float2 v = *(const float2*)&h[wid*HH + c0];
  float s = v.x + v.y;
  for (int m = 1; m <= 32; m <<= 1) s += __shfl_xor(s, m);
  float mu = s * (1.f/128.f);
  float dx = v.x - mu, dy = v.y - mu;
  float q = dx*dx + dy*dy;
  for (int m = 1; m <= 32; m <<= 1) q += __shfl_xor(q, m);
  float rs = rsqrtf(q * (1.f/128.f) + LN_EPS_);
  float2 o;
  o.x = fmaxf(dx*rs*g[c0]   + b[c0],   0.f);
  o.y = fmaxf(dy*rs*g[c0+1] + b[c0+1], 0.f);
  *(float2*)&out[wid*HH + c0] = o;
}

// ---------------- GENConv aggregation: wave per dst node, online softmax ----------------
__global__ __launch_bounds__(256) void conv_kernel(const float* __restrict__ hn, const int* __restrict__ off,
                                                   const int* __restrict__ srcs, const float4* __restrict__ ea4,
                                                   const float* __restrict__ eew, const float* __restrict__ eeb,
                                                   const float* __restrict__ t, int layer,
                                                   float* __restrict__ tmp) {
  int wid = blockIdx.x * 4 + (threadIdx.x >> 6);
  int lane = threadIdx.x & 63;
  if (wid >= NN) return;
  int c0 = lane * 2;
  float ti = t[layer];
  float w0x = eew[c0],      w0y = eew[c0+1];
  float w1x = eew[HH+c0],   w1y = eew[HH+c0+1];
  float w2x = eew[2*HH+c0], w2y = eew[2*HH+c0+1];
  float w3x = eew[3*HH+c0], w3y = eew[3*HH+c0+1];
  float bx = eeb[c0], by = eeb[c0+1];
  int e0 = off[wid], e1 = off[wid+1];
  float mx0 = -INFINITY, mx1 = -INFINITY;
  float den0 = 0.f, den1 = 0.f, num0 = 0.f, num1 = 0.f;
  for (int e = e0; e < e1; ++e) {
    int sidx = srcs[e];
    float4 a = ea4[e];
    float2 hs = *(const float2*)&hn[sidx*HH + c0];
    float eax = bx + a.x*w0x + a.y*w1x + a.z*w2x + a.w*w3x;
    float eay = by + a.x*w0y + a.y*w1y + a.z*w2y + a.w*w3y;
    float m0 = fmaxf(hs.x + eax, 0.f) + EPS_;
    float m1 = fmaxf(hs.y + eay, 0.f) + EPS_;
    float l0 = m0 * ti, l1 = m1 * ti;
    float n0 = fmaxf(mx0, l0), n1 = fmaxf(mx1, l1);
    float s0 = __expf(mx0 - n0), s1 = __expf(mx1 - n1);
    float p0 = __expf(l0 - n0),  p1 = __expf(l1 - n1);
    den0 = den0*s0 + p0;       den1 = den1*s1 + p1;
    num0 = num0*s0 + m0*p0;    num1 = num1*s1 + m1*p1;
    mx0 = n0; mx1 = n1;
  }
  float agg0 = num0 / (den0 + 1e-16f);
  float agg1 = num1 / (den1 + 1e-16f);
  float2 hd = *(const float2*)&hn[wid*HH + c0];
  float2 o; o.x = agg0 + hd.x; o.y = agg1 + hd.y;
  *(float2*)&tmp[wid*HH + c0] = o;
}

// ---------------- GEMM1 (Nx128 @ 128x256) fused bias+LN(256)+ReLU ----------------
#define G1R 32
__global__ __launch_bounds__(256) void gemm1_kernel(const float* __restrict__ A,
                                                    const float* __restrict__ W,
                                                    const float* __restrict__ bias,
                                                    const float* __restrict__ g, const float* __restrict__ bb,
                                                    float* __restrict__ U) {
  __shared__ float As[16][G1R + 4];   // transposed [kk][row]
  __shared__ float Bs[16][256];
  int tid = threadIdx.x;
  int r0 = blockIdx.x * G1R;
  int tx = tid & 31, ty = tid >> 5;
  float acc[4][8];
  #pragma unroll
  for (int i = 0; i < 4; ++i)
    #pragma unroll
    for (int j = 0; j < 8; ++j) acc[i][j] = 0.f;

  for (int k0 = 0; k0 < HH; k0 += 16) {
    {
      int r = tid >> 3;          // 0..31
      int kk = (tid & 7) * 2;    // 0..14
      int row = r0 + r;
      float2 v = (row < NN) ? *(const float2*)&A[row*HH + k0 + kk] : make_float2(0.f, 0.f);
      As[kk][r] = v.x; As[kk+1][r] = v.y;
    }
    {
      int kk = tid >> 4;         // 0..15
      int c = (tid & 15) * 16;
      const float4* s4 = (const float4*)&W[(k0+kk)*256 + c];
      float4* d4 = (float4*)&Bs[kk][c];
      d4[0] = s4[0]; d4[1] = s4[1]; d4[2] = s4[2]; d4[3] = s4[3];
    }
    __syncthreads();
    #pragma unroll
    for (int kk = 0; kk < 16; ++kk) {
      float a[4], b[8];
      #pragma unroll
      for (int i = 0; i < 4; ++i) a[i] = As[kk][ty*4 + i];
      #pragma unroll
      for (int j = 0; j < 8; ++j) b[j] = Bs[kk][tx*8 + j];
      #pragma unroll
      for (int i = 0; i < 4; ++i)
        #pragma unroll
        for (int j = 0; j < 8; ++j) acc[i][j] += a[i] * b[j];
    }
    __syncthreads();
  }
  float gj[8], bbj[8], bj[8];
  #pragma unroll
  for (int j = 0; j < 8; ++j) {
    int c = tx*8 + j;
    bj[j] = bias[c]; gj[j] = g[c]; bbj[j] = bb[c];
  }
  #pragma unroll
  for (int i = 0; i < 4; ++i) {
    int row = r0 + ty*4 + i;
    float xv[8], s = 0.f;
    #pragma unroll
    for (int j = 0; j < 8; ++j) { xv[j] = acc[i][j] + bj[j]; s += xv[j]; }
    for (int m = 1; m <= 16; m <<= 1) s += __shfl_xor(s, m);
    float mu = s * (1.f/256.f);
    float q = 0.f;
    #pragma unroll
    for (int j = 0; j < 8; ++j) { xv[j] -= mu; q += xv[j]*xv[j]; }
    for (int m = 1; m <= 16; m <<= 1) q += __shfl_xor(q, m);
    float rs = rsqrtf(q * (1.f/256.f) + LN_EPS_);
    float ov[8];
    #pragma unroll
    for (int j = 0; j < 8; ++j) ov[j] = fmaxf(xv[j]*rs*gj[j] + bbj[j], 0.f);
    if (row < NN) {
      float4* up = (float4*)&U[(size_t)row*256 + tx*8];
      up[0] = make_float4(ov[0], ov[1], ov[2], ov[3]);
      up[1] = make_float4(ov[4], ov[5], ov[6], ov[7]);
    }
  }
}

// ---------------- GEMM2 (Nx256 @ 256x128) + bias + residual ----------------
#define G2R 32
__global__ __launch_bounds__(256) void gemm2_kernel(const float* __restrict__ U,
                                                    const float* __restrict__ W,
                                                    const float* __restrict__ bias,
                                                    float* __restrict__ h, int first) {
  __shared__ float As[16][G2R + 4];
  __shared__ float Bs[16][128];
  int tid = threadIdx.x;
  int r0 = blockIdx.x * G2R;
  int tx = tid & 31, ty = tid >> 5;
  float acc[4][4];
  #pragma unroll
  for (int i = 0; i < 4; ++i)
    #pragma unroll
    for (int j = 0; j < 4; ++j) acc[i][j] = 0.f;

  for (int k0 = 0; k0 < 256; k0 += 16) {
    {
      int r = tid >> 3, kk = (tid & 7) * 2;
      int row = r0 + r;
      float2 v = (row < NN) ? *(const float2*)&U[(size_t)row*256 + k0 + kk] : make_float2(0.f, 0.f);
      As[kk][r] = v.x; As[kk+1][r] = v.y;
    }
    {
      int kb = tid >> 4;         // 0..15
      int c = (tid & 15) * 8;
      const float4* s4 = (const float4*)&W[(k0+kb)*HH + c];
      float4* d4 = (float4*)&Bs[kb][c];
      d4[0] = s4[0]; d4[1] = s4[1];
    }
    __syncthreads();
    #pragma unroll
    for (int kk = 0; kk < 16; ++kk) {
      float a[4], b[4];
      #pragma unroll
      for (int i = 0; i < 4; ++i) a[i] = As[kk][ty*4 + i];
      #pragma unroll
      for (int j = 0; j < 4; ++j) b[j] = Bs[kk][tx*4 + j];
      #pragma unroll
      for (int i = 0; i < 4; ++i)
        #pragma unroll
        for (int j = 0; j < 4; ++j) acc[i][j] += a[i] * b[j];
    }
    __syncthreads();
  }
  #pragma unroll
  for (int i = 0; i < 4; ++i) {
    int row = r0 + ty*4 + i;
    if (row >= NN) continue;
    #pragma unroll
    for (int j = 0; j < 4; ++j) {
      int c = tx*4 + j;
      float v = acc[i][j] + bias[c];
      if (!first) v += h[(size_t)row*HH + c];
      h[(size_t)row*HH + c] = v;
    }
  }
}

// ---------------- final output GEMM (Nx128 @ 128x16) ----------------
__global__ __launch_bounds__(256) void outgemm_kernel(const float* __restrict__ hn, const float* __restrict__ w,
                                                      const float* __restrict__ b, float* __restrict__ out) {
  __shared__ float Ws[HH * DOUT_];
  int tid = threadIdx.x;
  {
    const float4* s4 = (const float4*)w;
    float4* d4 = (float4*)Ws;
    d4[tid*2] = s4[tid*2]; d4[tid*2+1] = s4[tid*2+1];
  }
  __syncthreads();
  int id = blockIdx.x * 256 + tid;
  int n = id >> 4, c = id & 15;
  if (n >= NN) return;
  float s = b[c];
  const float* hr = &hn[(size_t)n*HH];
  #pragma unroll 8
  for (int k = 0; k < HH; ++k) s += hr[k] * Ws[k*DOUT_ + c];
  out[n*DOUT_ + c] = s;
}

extern "C" void kernel_launch(void* const* d_in, const int* in_sizes, int n_in,
                              void* d_out, int out_size, void* d_ws, size_t ws_size,
                              hipStream_t stream) {
  const float* x    = (const float*)d_in[0];
  const int*   ei   = (const int*)d_in[1];
  const float* eatt = (const float*)d_in[2];
  const float* enw  = (const float*)d_in[3];
  const float* enb  = (const float*)d_in[4];
  const float* eew  = (const float*)d_in[5];
  const float* eeb  = (const float*)d_in[6];
  const float* t    = (const float*)d_in[7];
  const float* m1w  = (const float*)d_in[8];
  const float* m1b  = (const float*)d_in[9];
  const float* mlg  = (const float*)d_in[10];
  const float* mlb  = (const float*)d_in[11];
  const float* m2w  = (const float*)d_in[12];
  const float* m2b  = (const float*)d_in[13];
  const float* lng  = (const float*)d_in[14];
  const float* lnb  = (const float*)d_in[15];
  const float* linw = (const float*)d_in[16];
  const float* linb = (const float*)d_in[17];
  float* out = (float*)d_out;

  char* ws = (char*)d_ws;
  size_t o = 0;
  auto take = [&](size_t bytes) { char* p = ws + o; o = (o + bytes + 255) & ~(size_t)255; return p; };
  int*    deg  = (int*)take((size_t)NN * 4);
  int*    off  = (int*)take((size_t)(NN + 1) * 4);
  int*    cur  = (int*)take((size_t)NN * 4);
  int*    srcs = (int*)take((size_t)EE * 4);
  float4* ea4  = (float4*)take((size_t)EE * 16);
  float*  h    = (float*)take((size_t)NN * HH * 4);
  float*  hnb  = (float*)take((size_t)NN * HH * 4);
  float*  tmp  = (float*)take((size_t)NN * HH * 4);
  float*  u    = (float*)take((size_t)NN * 256 * 4);

  const int* src = ei;
  const int* dst = ei + EE;

  hipMemsetAsync(deg, 0, (size_t)NN * 4, stream);
  hist_kernel<<<(EE + 255) / 256, 256, 0, stream>>>(dst, deg);
  scan_kernel<<<1, 1024, 0, stream>>>(deg, off, cur);
  scatter_kernel<<<(EE + 255) / 256, 256, 0, stream>>>(src, dst, (const float4*)eatt, cur, srcs, ea4);
  encoder_kernel<<<(NN * HH + 255) / 256, 256, 0, stream>>>(x, enw, enb, h);

  for (int i = 0; i < LL; ++i) {
    const float* cin = h;
    if (i > 0) {
      lnrelu_kernel<<<(NN + 3) / 4, 256, 0, stream>>>(h, lng + i * HH, lnb + i * HH, hnb);
      cin = hnb;
    }
    conv_kernel<<<(NN + 3) / 4, 256, 0, stream>>>(cin, off, srcs, ea4, eew, eeb, t, i, tmp);
    gemm1_kernel<<<(NN + G1R - 1) / G1R, 256, 0, stream>>>(tmp, m1w + (size_t)i * HH * 256,
                                                           m1b + i * 256, mlg + i * 256, mlb + i * 256, u);
    gemm2_kernel<<<(NN + G2R - 1) / G2R, 256, 0, stream>>>(u, m2w + (size_t)i * 256 * HH,
                                                           m2b + i * HH, h, i == 0 ? 1 : 0);
  }
  lnrelu_kernel<<<(NN + 3) / 4, 256, 0, stream>>>(h, lng, lnb, hnb);
  outgemm_kernel<<<(NN * DOUT_ + 255) / 256, 256, 0, stream>>>(hnb, linw, linb, out);
}

// Round 2
// 1613.329 us; speedup vs baseline: 1.2152x; 1.2152x over previous
//
#include <hip/hip_runtime.h>
#include <math.h>

#define NN 20000
#define EE 640000
#define HH 128
#define LL 12
#define DOUT_ 16
#define EPS_ 1e-7f
#define LN_EPS_ 1e-5f

// ---------------- CSR build ----------------
__global__ __launch_bounds__(256) void hist_kernel(const int* __restrict__ dst, int* __restrict__ deg) {
  int e = blockIdx.x * 256 + threadIdx.x;
  if (e < EE) atomicAdd(&deg[dst[e]], 1);
}

__global__ __launch_bounds__(1024) void scan_kernel(const int* __restrict__ deg, int* __restrict__ off,
                                                    int* __restrict__ cur) {
  __shared__ int part[1024];
  int tid = threadIdx.x;
  const int CH = (NN + 1023) >> 10;   // 20
  int base = tid * CH;
  int s = 0;
  for (int j = 0; j < CH; ++j) { int i = base + j; if (i < NN) s += deg[i]; }
  part[tid] = s;
  __syncthreads();
  for (int d = 1; d < 1024; d <<= 1) {
    int v = (tid >= d) ? part[tid - d] : 0;
    __syncthreads();
    part[tid] += v;
    __syncthreads();
  }
  int run = part[tid] - s;  // exclusive prefix
  for (int j = 0; j < CH; ++j) {
    int i = base + j;
    if (i < NN) { off[i] = run; cur[i] = run; run += deg[i]; }
  }
  if (tid == 1023) off[NN] = part[1023];
}

__global__ __launch_bounds__(256) void scatter_kernel(const int* __restrict__ src, const int* __restrict__ dst,
                                                      const float4* __restrict__ ea, int* __restrict__ cur,
                                                      int* __restrict__ srcs, float4* __restrict__ ea4) {
  int e = blockIdx.x * 256 + threadIdx.x;
  if (e >= EE) return;
  int d = dst[e];
  int p = atomicAdd(&cur[d], 1);
  srcs[p] = src[e];
  ea4[p] = ea[e];
}

// ---------------- encoders ----------------
__global__ __launch_bounds__(256) void encoder_kernel(const float* __restrict__ x, const float* __restrict__ w,
                                                      const float* __restrict__ b, float* __restrict__ h) {
  int id = blockIdx.x * 256 + threadIdx.x;
  if (id >= NN * HH) return;
  int n = id >> 7, c = id & 127;
  h[id] = b[c] + x[n*3+0]*w[c] + x[n*3+1]*w[HH+c] + x[n*3+2]*w[2*HH+c];
}

// ---------------- LN + ReLU over H=128 (wave per node) ----------------
__global__ __launch_bounds__(256) void lnrelu_kernel(const float* __restrict__ h, const float* __restrict__ g,
                                                     const float* __restrict__ b, float* __restrict__ out) {
  int wid = blockIdx.x * 4 + (threadIdx.x >> 6);
  int lane = threadIdx.x & 63;
  if (wid >= NN) return;
  int c0 = lane * 2;
  float2 v = *(const float2*)&h[wid*HH + c0];
  float s = v.x + v.y;
  for (int m = 1; m <= 32; m <<= 1) s += __shfl_xor(s, m);
  float mu = s * (1.f/128.f);
  float dx = v.x - mu, dy = v.y - mu;
  float q = dx*dx + dy*dy;
  for (int m = 1; m <= 32; m <<= 1) q += __shfl_xor(q, m);
  float rs = rsqrtf(q * (1.f/128.f) + LN_EPS_);
  float2 o;
  o.x = fmaxf(dx*rs*g[c0]   + b[c0],   0.f);
  o.y = fmaxf(dy*rs*g[c0+1] + b[c0+1], 0.f);
  *(float2*)&out[wid*HH + c0] = o;
}

// ---------------- GENConv aggregation: wave per dst node ----------------
// Direct-exp softmax (no running-max): logits are bounded (~<20) because conv
// input is relu(LN(h)) [+ encoder-scale edge attr], so exp() cannot overflow
// fp32. num/den ratio is algebraically identical to the max-subtracted form;
// empty segments give 0/(0+1e-16)=0 matching the reference guard.
// Edge loop unrolled by 8 so 8 hn-gathers are in flight per wave.
__global__ __launch_bounds__(256) void conv_kernel(const float* __restrict__ hn, const int* __restrict__ off,
                                                   const int* __restrict__ srcs, const float4* __restrict__ ea4,
                                                   const float* __restrict__ eew, const float* __restrict__ eeb,
                                                   const float* __restrict__ t, int layer,
                                                   float* __restrict__ tmp) {
  int wid = blockIdx.x * 4 + (threadIdx.x >> 6);
  int lane = threadIdx.x & 63;
  if (wid >= NN) return;
  int c0 = lane * 2;
  float ti = t[layer];
  float w0x = eew[c0],      w0y = eew[c0+1];
  float w1x = eew[HH+c0],   w1y = eew[HH+c0+1];
  float w2x = eew[2*HH+c0], w2y = eew[2*HH+c0+1];
  float w3x = eew[3*HH+c0], w3y = eew[3*HH+c0+1];
  float bx = eeb[c0], by = eeb[c0+1];
  int e0 = off[wid], e1 = off[wid+1];
  float2 hd = *(const float2*)&hn[(size_t)wid*HH + c0];
  float den0 = 0.f, den1 = 0.f, num0 = 0.f, num1 = 0.f;

  int e = e0;
  const int UF = 8;
  for (; e + UF <= e1; e += UF) {
    int si[UF]; float4 av[UF]; float2 hv[UF];
    #pragma unroll
    for (int u = 0; u < UF; ++u) { si[u] = srcs[e + u]; av[u] = ea4[e + u]; }
    #pragma unroll
    for (int u = 0; u < UF; ++u) hv[u] = *(const float2*)&hn[(size_t)si[u]*HH + c0];
    #pragma unroll
    for (int u = 0; u < UF; ++u) {
      float eax = fmaf(av[u].w, w3x, fmaf(av[u].z, w2x, fmaf(av[u].y, w1x, fmaf(av[u].x, w0x, bx))));
      float eay = fmaf(av[u].w, w3y, fmaf(av[u].z, w2y, fmaf(av[u].y, w1y, fmaf(av[u].x, w0y, by))));
      float m0 = fmaxf(hv[u].x + eax, 0.f) + EPS_;
      float m1 = fmaxf(hv[u].y + eay, 0.f) + EPS_;
      float p0 = __expf(m0 * ti);
      float p1 = __expf(m1 * ti);
      den0 += p0; den1 += p1;
      num0 = fmaf(m0, p0, num0);
      num1 = fmaf(m1, p1, num1);
    }
  }
  for (; e < e1; ++e) {
    int sidx = srcs[e];
    float4 a = ea4[e];
    float2 hs = *(const float2*)&hn[(size_t)sidx*HH + c0];
    float eax = fmaf(a.w, w3x, fmaf(a.z, w2x, fmaf(a.y, w1x, fmaf(a.x, w0x, bx))));
    float eay = fmaf(a.w, w3y, fmaf(a.z, w2y, fmaf(a.y, w1y, fmaf(a.x, w0y, by))));
    float m0 = fmaxf(hs.x + eax, 0.f) + EPS_;
    float m1 = fmaxf(hs.y + eay, 0.f) + EPS_;
    float p0 = __expf(m0 * ti);
    float p1 = __expf(m1 * ti);
    den0 += p0; den1 += p1;
    num0 = fmaf(m0, p0, num0);
    num1 = fmaf(m1, p1, num1);
  }
  float agg0 = num0 / (den0 + 1e-16f);
  float agg1 = num1 / (den1 + 1e-16f);
  *(float2*)&tmp[(size_t)wid*HH + c0] = make_float2(agg0 + hd.x, agg1 + hd.y);
}

// ---------------- GEMM1 (Nx128 @ 128x256) fused bias+LN(256)+ReLU ----------------
#define G1R 32
__global__ __launch_bounds__(256) void gemm1_kernel(const float* __restrict__ A,
                                                    const float* __restrict__ W,
                                                    const float* __restrict__ bias,
                                                    const float* __restrict__ g, const float* __restrict__ bb,
                                                    float* __restrict__ U) {
  __shared__ float As[16][G1R + 4];   // transposed [kk][row]
  __shared__ float Bs[16][256];
  int tid = threadIdx.x;
  int r0 = blockIdx.x * G1R;
  int tx = tid & 31, ty = tid >> 5;
  float acc[4][8];
  #pragma unroll
  for (int i = 0; i < 4; ++i)
    #pragma unroll
    for (int j = 0; j < 8; ++j) acc[i][j] = 0.f;

  for (int k0 = 0; k0 < HH; k0 += 16) {
    {
      int r = tid >> 3;          // 0..31
      int kk = (tid & 7) * 2;    // 0..14
      int row = r0 + r;
      float2 v = (row < NN) ? *(const float2*)&A[row*HH + k0 + kk] : make_float2(0.f, 0.f);
      As[kk][r] = v.x; As[kk+1][r] = v.y;
    }
    {
      int kk = tid >> 4;         // 0..15
      int c = (tid & 15) * 16;
      const float4* s4 = (const float4*)&W[(k0+kk)*256 + c];
      float4* d4 = (float4*)&Bs[kk][c];
      d4[0] = s4[0]; d4[1] = s4[1]; d4[2] = s4[2]; d4[3] = s4[3];
    }
    __syncthreads();
    #pragma unroll
    for (int kk = 0; kk < 16; ++kk) {
      float a[4], b[8];
      #pragma unroll
      for (int i = 0; i < 4; ++i) a[i] = As[kk][ty*4 + i];
      #pragma unroll
      for (int j = 0; j < 8; ++j) b[j] = Bs[kk][tx*8 + j];
      #pragma unroll
      for (int i = 0; i < 4; ++i)
        #pragma unroll
        for (int j = 0; j < 8; ++j) acc[i][j] += a[i] * b[j];
    }
    __syncthreads();
  }
  float gj[8], bbj[8], bj[8];
  #pragma unroll
  for (int j = 0; j < 8; ++j) {
    int c = tx*8 + j;
    bj[j] = bias[c]; gj[j] = g[c]; bbj[j] = bb[c];
  }
  #pragma unroll
  for (int i = 0; i < 4; ++i) {
    int row = r0 + ty*4 + i;
    float xv[8], s = 0.f;
    #pragma unroll
    for (int j = 0; j < 8; ++j) { xv[j] = acc[i][j] + bj[j]; s += xv[j]; }
    for (int m = 1; m <= 16; m <<= 1) s += __shfl_xor(s, m);
    float mu = s * (1.f/256.f);
    float q = 0.f;
    #pragma unroll
    for (int j = 0; j < 8; ++j) { xv[j] -= mu; q += xv[j]*xv[j]; }
    for (int m = 1; m <= 16; m <<= 1) q += __shfl_xor(q, m);
    float rs = rsqrtf(q * (1.f/256.f) + LN_EPS_);
    float ov[8];
    #pragma unroll
    for (int j = 0; j < 8; ++j) ov[j] = fmaxf(xv[j]*rs*gj[j] + bbj[j], 0.f);
    if (row < NN) {
      float4* up = (float4*)&U[(size_t)row*256 + tx*8];
      up[0] = make_float4(ov[0], ov[1], ov[2], ov[3]);
      up[1] = make_float4(ov[4], ov[5], ov[6], ov[7]);
    }
  }
}

// ---------------- GEMM2 (Nx256 @ 256x128) + bias + residual ----------------
#define G2R 32
__global__ __launch_bounds__(256) void gemm2_kernel(const float* __restrict__ U,
                                                    const float* __restrict__ W,
                                                    const float* __restrict__ bias,
                                                    float* __restrict__ h, int first) {
  __shared__ float As[16][G2R + 4];
  __shared__ float Bs[16][128];
  int tid = threadIdx.x;
  int r0 = blockIdx.x * G2R;
  int tx = tid & 31, ty = tid >> 5;
  float acc[4][4];
  #pragma unroll
  for (int i = 0; i < 4; ++i)
    #pragma unroll
    for (int j = 0; j < 4; ++j) acc[i][j] = 0.f;

  for (int k0 = 0; k0 < 256; k0 += 16) {
    {
      int r = tid >> 3, kk = (tid & 7) * 2;
      int row = r0 + r;
      float2 v = (row < NN) ? *(const float2*)&U[(size_t)row*256 + k0 + kk] : make_float2(0.f, 0.f);
      As[kk][r] = v.x; As[kk+1][r] = v.y;
    }
    {
      int kb = tid >> 4;         // 0..15
      int c = (tid & 15) * 8;
      const float4* s4 = (const float4*)&W[(k0+kb)*HH + c];
      float4* d4 = (float4*)&Bs[kb][c];
      d4[0] = s4[0]; d4[1] = s4[1];
    }
    __syncthreads();
    #pragma unroll
    for (int kk = 0; kk < 16; ++kk) {
      float a[4], b[4];
      #pragma unroll
      for (int i = 0; i < 4; ++i) a[i] = As[kk][ty*4 + i];
      #pragma unroll
      for (int j = 0; j < 4; ++j) b[j] = Bs[kk][tx*4 + j];
      #pragma unroll
      for (int i = 0; i < 4; ++i)
        #pragma unroll
        for (int j = 0; j < 4; ++j) acc[i][j] += a[i] * b[j];
    }
    __syncthreads();
  }
  #pragma unroll
  for (int i = 0; i < 4; ++i) {
    int row = r0 + ty*4 + i;
    if (row >= NN) continue;
    #pragma unroll
    for (int j = 0; j < 4; ++j) {
      int c = tx*4 + j;
      float v = acc[i][j] + bias[c];
      if (!first) v += h[(size_t)row*HH + c];
      h[(size_t)row*HH + c] = v;
    }
  }
}

// ---------------- final output GEMM (Nx128 @ 128x16) ----------------
__global__ __launch_bounds__(256) void outgemm_kernel(const float* __restrict__ hn, const float* __restrict__ w,
                                                      const float* __restrict__ b, float* __restrict__ out) {
  __shared__ float Ws[HH * DOUT_];
  int tid = threadIdx.x;
  {
    const float4* s4 = (const float4*)w;
    float4* d4 = (float4*)Ws;
    d4[tid*2] = s4[tid*2]; d4[tid*2+1] = s4[tid*2+1];
  }
  __syncthreads();
  int id = blockIdx.x * 256 + tid;
  int n = id >> 4, c = id & 15;
  if (n >= NN) return;
  float s = b[c];
  const float* hr = &hn[(size_t)n*HH];
  #pragma unroll 8
  for (int k = 0; k < HH; ++k) s += hr[k] * Ws[k*DOUT_ + c];
  out[n*DOUT_ + c] = s;
}

extern "C" void kernel_launch(void* const* d_in, const int* in_sizes, int n_in,
                              void* d_out, int out_size, void* d_ws, size_t ws_size,
                              hipStream_t stream) {
  const float* x    = (const float*)d_in[0];
  const int*   ei   = (const int*)d_in[1];
  const float* eatt = (const float*)d_in[2];
  const float* enw  = (const float*)d_in[3];
  const float* enb  = (const float*)d_in[4];
  const float* eew  = (const float*)d_in[5];
  const float* eeb  = (const float*)d_in[6];
  const float* t    = (const float*)d_in[7];
  const float* m1w  = (const float*)d_in[8];
  const float* m1b  = (const float*)d_in[9];
  const float* mlg  = (const float*)d_in[10];
  const float* mlb  = (const float*)d_in[11];
  const float* m2w  = (const float*)d_in[12];
  const float* m2b  = (const float*)d_in[13];
  const float* lng  = (const float*)d_in[14];
  const float* lnb  = (const float*)d_in[15];
  const float* linw = (const float*)d_in[16];
  const float* linb = (const float*)d_in[17];
  float* out = (float*)d_out;

  char* ws = (char*)d_ws;
  size_t o = 0;
  auto take = [&](size_t bytes) { char* p = ws + o; o = (o + bytes + 255) & ~(size_t)255; return p; };
  int*    deg  = (int*)take((size_t)NN * 4);
  int*    off  = (int*)take((size_t)(NN + 1) * 4);
  int*    cur  = (int*)take((size_t)NN * 4);
  int*    srcs = (int*)take((size_t)EE * 4);
  float4* ea4  = (float4*)take((size_t)EE * 16);
  float*  h    = (float*)take((size_t)NN * HH * 4);
  float*  hnb  = (float*)take((size_t)NN * HH * 4);
  float*  tmp  = (float*)take((size_t)NN * HH * 4);
  float*  u    = (float*)take((size_t)NN * 256 * 4);

  const int* src = ei;
  const int* dst = ei + EE;

  hipMemsetAsync(deg, 0, (size_t)NN * 4, stream);
  hist_kernel<<<(EE + 255) / 256, 256, 0, stream>>>(dst, deg);
  scan_kernel<<<1, 1024, 0, stream>>>(deg, off, cur);
  scatter_kernel<<<(EE + 255) / 256, 256, 0, stream>>>(src, dst, (const float4*)eatt, cur, srcs, ea4);
  encoder_kernel<<<(NN * HH + 255) / 256, 256, 0, stream>>>(x, enw, enb, h);

  for (int i = 0; i < LL; ++i) {
    const float* cin = h;
    if (i > 0) {
      lnrelu_kernel<<<(NN + 3) / 4, 256, 0, stream>>>(h, lng + i * HH, lnb + i * HH, hnb);
      cin = hnb;
    }
    conv_kernel<<<(NN + 3) / 4, 256, 0, stream>>>(cin, off, srcs, ea4, eew, eeb, t, i, tmp);
    gemm1_kernel<<<(NN + G1R - 1) / G1R, 256, 0, stream>>>(tmp, m1w + (size_t)i * HH * 256,
                                                           m1b + i * 256, mlg + i * 256, mlb + i * 256, u);
    gemm2_kernel<<<(NN + G2R - 1) / G2R, 256, 0, stream>>>(u, m2w + (size_t)i * 256 * HH,
                                                           m2b + i * HH, h, i == 0 ? 1 : 0);
  }
  lnrelu_kernel<<<(NN + 3) / 4, 256, 0, stream>>>(h, lng, lnb, hnb);
  outgemm_kernel<<<(NN * DOUT_ + 255) / 256, 256, 0, stream>>>(hnb, linw, linb, out);
}

// Round 3
// 1481.915 us; speedup vs baseline: 1.3229x; 1.0887x over previous
//
#include <hip/hip_runtime.h>
#include <hip/hip_bf16.h>
#include <math.h>

#define NN 20000
#define EE 640000
#define HH 128
#define LL 12
#define DOUT_ 16
#define EPS_ 1e-7f
#define LN_EPS_ 1e-5f

// ---------------- CSR build ----------------
__global__ __launch_bounds__(256) void hist_kernel(const int* __restrict__ dst, int* __restrict__ deg) {
  int e = blockIdx.x * 256 + threadIdx.x;
  if (e < EE) atomicAdd(&deg[dst[e]], 1);
}

__global__ __launch_bounds__(1024) void scan_kernel(const int* __restrict__ deg, int* __restrict__ off,
                                                    int* __restrict__ cur) {
  __shared__ int part[1024];
  int tid = threadIdx.x;
  const int CH = (NN + 1023) >> 10;   // 20
  int base = tid * CH;
  int s = 0;
  for (int j = 0; j < CH; ++j) { int i = base + j; if (i < NN) s += deg[i]; }
  part[tid] = s;
  __syncthreads();
  for (int d = 1; d < 1024; d <<= 1) {
    int v = (tid >= d) ? part[tid - d] : 0;
    __syncthreads();
    part[tid] += v;
    __syncthreads();
  }
  int run = part[tid] - s;  // exclusive prefix
  for (int j = 0; j < CH; ++j) {
    int i = base + j;
    if (i < NN) { off[i] = run; cur[i] = run; run += deg[i]; }
  }
  if (tid == 1023) off[NN] = part[1023];
}

__global__ __launch_bounds__(256) void scatter_kernel(const int* __restrict__ src, const int* __restrict__ dst,
                                                      const float4* __restrict__ ea, int* __restrict__ cur,
                                                      int* __restrict__ srcs, float4* __restrict__ ea4) {
  int e = blockIdx.x * 256 + threadIdx.x;
  if (e >= EE) return;
  int d = dst[e];
  int p = atomicAdd(&cur[d], 1);
  srcs[p] = src[e];
  ea4[p] = ea[e];
}

// ---------------- encoders ----------------
// writes fp32 h and packed-bf16 copy hb (for conv gathers)
__global__ __launch_bounds__(256) void encoder_kernel(const float* __restrict__ x, const float* __restrict__ w,
                                                      const float* __restrict__ b, float* __restrict__ h,
                                                      __hip_bfloat162* __restrict__ hb) {
  int id = blockIdx.x * 256 + threadIdx.x;
  if (id >= NN * 64) return;
  int n = id >> 6, cp = id & 63;
  int c0 = cp * 2;
  float x0 = x[n*3+0], x1 = x[n*3+1], x2 = x[n*3+2];
  float vx = b[c0]   + x0*w[c0]   + x1*w[HH+c0]   + x2*w[2*HH+c0];
  float vy = b[c0+1] + x0*w[c0+1] + x1*w[HH+c0+1] + x2*w[2*HH+c0+1];
  *(float2*)&h[(size_t)n*HH + c0] = make_float2(vx, vy);
  hb[(size_t)n*64 + cp] = __hip_bfloat162(__float2bfloat16(vx), __float2bfloat16(vy));
}

// ---------------- LN + ReLU over H=128 (wave per node) ----------------
// writes fp32 out (dst-side residual read in conv / outgemm input) and bf16 hb
__global__ __launch_bounds__(256) void lnrelu_kernel(const float* __restrict__ h, const float* __restrict__ g,
                                                     const float* __restrict__ b, float* __restrict__ out,
                                                     __hip_bfloat162* __restrict__ hb) {
  int wid = blockIdx.x * 4 + (threadIdx.x >> 6);
  int lane = threadIdx.x & 63;
  if (wid >= NN) return;
  int c0 = lane * 2;
  float2 v = *(const float2*)&h[(size_t)wid*HH + c0];
  float s = v.x + v.y;
  for (int m = 1; m <= 32; m <<= 1) s += __shfl_xor(s, m);
  float mu = s * (1.f/128.f);
  float dx = v.x - mu, dy = v.y - mu;
  float q = dx*dx + dy*dy;
  for (int m = 1; m <= 32; m <<= 1) q += __shfl_xor(q, m);
  float rs = rsqrtf(q * (1.f/128.f) + LN_EPS_);
  float ox = fmaxf(dx*rs*g[c0]   + b[c0],   0.f);
  float oy = fmaxf(dy*rs*g[c0+1] + b[c0+1], 0.f);
  *(float2*)&out[(size_t)wid*HH + c0] = make_float2(ox, oy);
  hb[(size_t)wid*64 + lane] = __hip_bfloat162(__float2bfloat16(ox), __float2bfloat16(oy));
}

// ---------------- GENConv aggregation: wave per dst node ----------------
// Direct-exp softmax (no running-max): logits bounded (input is relu(LN(h))),
// exp cannot overflow fp32; ratio identical to max-subtracted form.
// Gathers read the packed-bf16 table (4 B/lane) -> halved gather traffic and
// the 5.1 MB table is ~L2-resident. Edge loop unrolled x8 for MLP.
__global__ __launch_bounds__(256) void conv_kernel(const float* __restrict__ hn,
                                                   const __hip_bfloat162* __restrict__ hb,
                                                   const int* __restrict__ off,
                                                   const int* __restrict__ srcs, const float4* __restrict__ ea4,
                                                   const float* __restrict__ eew, const float* __restrict__ eeb,
                                                   const float* __restrict__ t, int layer,
                                                   float* __restrict__ tmp) {
  int wid = blockIdx.x * 4 + (threadIdx.x >> 6);
  int lane = threadIdx.x & 63;
  if (wid >= NN) return;
  int c0 = lane * 2;
  float ti = t[layer];
  float w0x = eew[c0],      w0y = eew[c0+1];
  float w1x = eew[HH+c0],   w1y = eew[HH+c0+1];
  float w2x = eew[2*HH+c0], w2y = eew[2*HH+c0+1];
  float w3x = eew[3*HH+c0], w3y = eew[3*HH+c0+1];
  float bx = eeb[c0], by = eeb[c0+1];
  int e0 = off[wid], e1 = off[wid+1];
  float2 hd = *(const float2*)&hn[(size_t)wid*HH + c0];
  float den0 = 0.f, den1 = 0.f, num0 = 0.f, num1 = 0.f;

  int e = e0;
  const int UF = 8;
  for (; e + UF <= e1; e += UF) {
    int si[UF]; float4 av[UF]; __hip_bfloat162 hv[UF];
    #pragma unroll
    for (int u = 0; u < UF; ++u) { si[u] = srcs[e + u]; av[u] = ea4[e + u]; }
    #pragma unroll
    for (int u = 0; u < UF; ++u) hv[u] = hb[(size_t)si[u]*64 + lane];
    #pragma unroll
    for (int u = 0; u < UF; ++u) {
      float hx = __bfloat162float(hv[u].x);
      float hy = __bfloat162float(hv[u].y);
      float eax = fmaf(av[u].w, w3x, fmaf(av[u].z, w2x, fmaf(av[u].y, w1x, fmaf(av[u].x, w0x, bx))));
      float eay = fmaf(av[u].w, w3y, fmaf(av[u].z, w2y, fmaf(av[u].y, w1y, fmaf(av[u].x, w0y, by))));
      float m0 = fmaxf(hx + eax, 0.f) + EPS_;
      float m1 = fmaxf(hy + eay, 0.f) + EPS_;
      float p0 = __expf(m0 * ti);
      float p1 = __expf(m1 * ti);
      den0 += p0; den1 += p1;
      num0 = fmaf(m0, p0, num0);
      num1 = fmaf(m1, p1, num1);
    }
  }
  for (; e < e1; ++e) {
    int sidx = srcs[e];
    float4 a = ea4[e];
    __hip_bfloat162 hv = hb[(size_t)sidx*64 + lane];
    float hx = __bfloat162float(hv.x);
    float hy = __bfloat162float(hv.y);
    float eax = fmaf(a.w, w3x, fmaf(a.z, w2x, fmaf(a.y, w1x, fmaf(a.x, w0x, bx))));
    float eay = fmaf(a.w, w3y, fmaf(a.z, w2y, fmaf(a.y, w1y, fmaf(a.x, w0y, by))));
    float m0 = fmaxf(hx + eax, 0.f) + EPS_;
    float m1 = fmaxf(hy + eay, 0.f) + EPS_;
    float p0 = __expf(m0 * ti);
    float p1 = __expf(m1 * ti);
    den0 += p0; den1 += p1;
    num0 = fmaf(m0, p0, num0);
    num1 = fmaf(m1, p1, num1);
  }
  float agg0 = num0 / (den0 + 1e-16f);
  float agg1 = num1 / (den1 + 1e-16f);
  *(float2*)&tmp[(size_t)wid*HH + c0] = make_float2(agg0 + hd.x, agg1 + hd.y);
}

// ---------------- GEMM1 (Nx128 @ 128x256) fused bias+LN(256)+ReLU ----------------
#define G1R 32
__global__ __launch_bounds__(256) void gemm1_kernel(const float* __restrict__ A,
                                                    const float* __restrict__ W,
                                                    const float* __restrict__ bias,
                                                    const float* __restrict__ g, const float* __restrict__ bb,
                                                    float* __restrict__ U) {
  __shared__ float As[16][G1R + 4];   // transposed [kk][row]
  __shared__ float Bs[16][256];
  int tid = threadIdx.x;
  int r0 = blockIdx.x * G1R;
  int tx = tid & 31, ty = tid >> 5;
  float acc[4][8];
  #pragma unroll
  for (int i = 0; i < 4; ++i)
    #pragma unroll
    for (int j = 0; j < 8; ++j) acc[i][j] = 0.f;

  for (int k0 = 0; k0 < HH; k0 += 16) {
    {
      int r = tid >> 3;          // 0..31
      int kk = (tid & 7) * 2;    // 0..14
      int row = r0 + r;
      float2 v = (row < NN) ? *(const float2*)&A[row*HH + k0 + kk] : make_float2(0.f, 0.f);
      As[kk][r] = v.x; As[kk+1][r] = v.y;
    }
    {
      int kk = tid >> 4;         // 0..15
      int c = (tid & 15) * 16;
      const float4* s4 = (const float4*)&W[(k0+kk)*256 + c];
      float4* d4 = (float4*)&Bs[kk][c];
      d4[0] = s4[0]; d4[1] = s4[1]; d4[2] = s4[2]; d4[3] = s4[3];
    }
    __syncthreads();
    #pragma unroll
    for (int kk = 0; kk < 16; ++kk) {
      float a[4], b[8];
      #pragma unroll
      for (int i = 0; i < 4; ++i) a[i] = As[kk][ty*4 + i];
      #pragma unroll
      for (int j = 0; j < 8; ++j) b[j] = Bs[kk][tx*8 + j];
      #pragma unroll
      for (int i = 0; i < 4; ++i)
        #pragma unroll
        for (int j = 0; j < 8; ++j) acc[i][j] += a[i] * b[j];
    }
    __syncthreads();
  }
  float gj[8], bbj[8], bj[8];
  #pragma unroll
  for (int j = 0; j < 8; ++j) {
    int c = tx*8 + j;
    bj[j] = bias[c]; gj[j] = g[c]; bbj[j] = bb[c];
  }
  #pragma unroll
  for (int i = 0; i < 4; ++i) {
    int row = r0 + ty*4 + i;
    float xv[8], s = 0.f;
    #pragma unroll
    for (int j = 0; j < 8; ++j) { xv[j] = acc[i][j] + bj[j]; s += xv[j]; }
    for (int m = 1; m <= 16; m <<= 1) s += __shfl_xor(s, m);
    float mu = s * (1.f/256.f);
    float q = 0.f;
    #pragma unroll
    for (int j = 0; j < 8; ++j) { xv[j] -= mu; q += xv[j]*xv[j]; }
    for (int m = 1; m <= 16; m <<= 1) q += __shfl_xor(q, m);
    float rs = rsqrtf(q * (1.f/256.f) + LN_EPS_);
    float ov[8];
    #pragma unroll
    for (int j = 0; j < 8; ++j) ov[j] = fmaxf(xv[j]*rs*gj[j] + bbj[j], 0.f);
    if (row < NN) {
      float4* up = (float4*)&U[(size_t)row*256 + tx*8];
      up[0] = make_float4(ov[0], ov[1], ov[2], ov[3]);
      up[1] = make_float4(ov[4], ov[5], ov[6], ov[7]);
    }
  }
}

// ---------------- GEMM2 (Nx256 @ 256x128) + bias + residual ----------------
#define G2R 32
__global__ __launch_bounds__(256) void gemm2_kernel(const float* __restrict__ U,
                                                    const float* __restrict__ W,
                                                    const float* __restrict__ bias,
                                                    float* __restrict__ h, int first) {
  __shared__ float As[16][G2R + 4];
  __shared__ float Bs[16][128];
  int tid = threadIdx.x;
  int r0 = blockIdx.x * G2R;
  int tx = tid & 31, ty = tid >> 5;
  float acc[4][4];
  #pragma unroll
  for (int i = 0; i < 4; ++i)
    #pragma unroll
    for (int j = 0; j < 4; ++j) acc[i][j] = 0.f;

  for (int k0 = 0; k0 < 256; k0 += 16) {
    {
      int r = tid >> 3, kk = (tid & 7) * 2;
      int row = r0 + r;
      float2 v = (row < NN) ? *(const float2*)&U[(size_t)row*256 + k0 + kk] : make_float2(0.f, 0.f);
      As[kk][r] = v.x; As[kk+1][r] = v.y;
    }
    {
      int kb = tid >> 4;         // 0..15
      int c = (tid & 15) * 8;
      const float4* s4 = (const float4*)&W[(k0+kb)*HH + c];
      float4* d4 = (float4*)&Bs[kb][c];
      d4[0] = s4[0]; d4[1] = s4[1];
    }
    __syncthreads();
    #pragma unroll
    for (int kk = 0; kk < 16; ++kk) {
      float a[4], b[4];
      #pragma unroll
      for (int i = 0; i < 4; ++i) a[i] = As[kk][ty*4 + i];
      #pragma unroll
      for (int j = 0; j < 4; ++j) b[j] = Bs[kk][tx*4 + j];
      #pragma unroll
      for (int i = 0; i < 4; ++i)
        #pragma unroll
        for (int j = 0; j < 4; ++j) acc[i][j] += a[i] * b[j];
    }
    __syncthreads();
  }
  #pragma unroll
  for (int i = 0; i < 4; ++i) {
    int row = r0 + ty*4 + i;
    if (row >= NN) continue;
    #pragma unroll
    for (int j = 0; j < 4; ++j) {
      int c = tx*4 + j;
      float v = acc[i][j] + bias[c];
      if (!first) v += h[(size_t)row*HH + c];
      h[(size_t)row*HH + c] = v;
    }
  }
}

// ---------------- final output GEMM (Nx128 @ 128x16) ----------------
__global__ __launch_bounds__(256) void outgemm_kernel(const float* __restrict__ hn, const float* __restrict__ w,
                                                      const float* __restrict__ b, float* __restrict__ out) {
  __shared__ float Ws[HH * DOUT_];
  int tid = threadIdx.x;
  {
    const float4* s4 = (const float4*)w;
    float4* d4 = (float4*)Ws;
    d4[tid*2] = s4[tid*2]; d4[tid*2+1] = s4[tid*2+1];
  }
  __syncthreads();
  int id = blockIdx.x * 256 + tid;
  int n = id >> 4, c = id & 15;
  if (n >= NN) return;
  float s = b[c];
  const float* hr = &hn[(size_t)n*HH];
  #pragma unroll 8
  for (int k = 0; k < HH; ++k) s += hr[k] * Ws[k*DOUT_ + c];
  out[n*DOUT_ + c] = s;
}

extern "C" void kernel_launch(void* const* d_in, const int* in_sizes, int n_in,
                              void* d_out, int out_size, void* d_ws, size_t ws_size,
                              hipStream_t stream) {
  const float* x    = (const float*)d_in[0];
  const int*   ei   = (const int*)d_in[1];
  const float* eatt = (const float*)d_in[2];
  const float* enw  = (const float*)d_in[3];
  const float* enb  = (const float*)d_in[4];
  const float* eew  = (const float*)d_in[5];
  const float* eeb  = (const float*)d_in[6];
  const float* t    = (const float*)d_in[7];
  const float* m1w  = (const float*)d_in[8];
  const float* m1b  = (const float*)d_in[9];
  const float* mlg  = (const float*)d_in[10];
  const float* mlb  = (const float*)d_in[11];
  const float* m2w  = (const float*)d_in[12];
  const float* m2b  = (const float*)d_in[13];
  const float* lng  = (const float*)d_in[14];
  const float* lnb  = (const float*)d_in[15];
  const float* linw = (const float*)d_in[16];
  const float* linb = (const float*)d_in[17];
  float* out = (float*)d_out;

  char* ws = (char*)d_ws;
  size_t o = 0;
  auto take = [&](size_t bytes) { char* p = ws + o; o = (o + bytes + 255) & ~(size_t)255; return p; };
  int*    deg  = (int*)take((size_t)NN * 4);
  int*    off  = (int*)take((size_t)(NN + 1) * 4);
  int*    cur  = (int*)take((size_t)NN * 4);
  int*    srcs = (int*)take((size_t)EE * 4);
  float4* ea4  = (float4*)take((size_t)EE * 16);
  float*  h    = (float*)take((size_t)NN * HH * 4);
  float*  hnb  = (float*)take((size_t)NN * HH * 4);
  float*  tmp  = (float*)take((size_t)NN * HH * 4);
  float*  u    = (float*)take((size_t)NN * 256 * 4);
  __hip_bfloat162* hb = (__hip_bfloat162*)take((size_t)NN * 64 * 4);

  const int* src = ei;
  const int* dst = ei + EE;

  hipMemsetAsync(deg, 0, (size_t)NN * 4, stream);
  hist_kernel<<<(EE + 255) / 256, 256, 0, stream>>>(dst, deg);
  scan_kernel<<<1, 1024, 0, stream>>>(deg, off, cur);
  scatter_kernel<<<(EE + 255) / 256, 256, 0, stream>>>(src, dst, (const float4*)eatt, cur, srcs, ea4);
  encoder_kernel<<<(NN * 64 + 255) / 256, 256, 0, stream>>>(x, enw, enb, h, hb);

  for (int i = 0; i < LL; ++i) {
    const float* cin = h;
    if (i > 0) {
      lnrelu_kernel<<<(NN + 3) / 4, 256, 0, stream>>>(h, lng + i * HH, lnb + i * HH, hnb, hb);
      cin = hnb;
    }
    conv_kernel<<<(NN + 3) / 4, 256, 0, stream>>>(cin, hb, off, srcs, ea4, eew, eeb, t, i, tmp);
    gemm1_kernel<<<(NN + G1R - 1) / G1R, 256, 0, stream>>>(tmp, m1w + (size_t)i * HH * 256,
                                                           m1b + i * 256, mlg + i * 256, mlb + i * 256, u);
    gemm2_kernel<<<(NN + G2R - 1) / G2R, 256, 0, stream>>>(u, m2w + (size_t)i * 256 * HH,
                                                           m2b + i * HH, h, i == 0 ? 1 : 0);
  }
  lnrelu_kernel<<<(NN + 3) / 4, 256, 0, stream>>>(h, lng, lnb, hnb, hb);
  outgemm_kernel<<<(NN * DOUT_ + 255) / 256, 256, 0, stream>>>(hnb, linw, linb, out);
}